// Round 7
// baseline (159.127 us; speedup 1.0000x reference)
//
#include <hip/hip_runtime.h>
#include <stdint.h>

typedef __bf16 v8bf __attribute__((ext_vector_type(8)));
typedef float  v4f  __attribute__((ext_vector_type(4)));
typedef int    v4i  __attribute__((ext_vector_type(4)));
typedef unsigned short u16;
typedef unsigned char  u8;

static constexpr int B_ = 4, S_ = 4096, D_ = 256, E_ = 512;
// i8 symmetric quant: clip 4.8 (~5.9 sigma of q/k), Delta = 4.8/127
static constexpr float QSC_ = 127.0f / 4.8f;          // quant scale
static constexpr float DQ_  = 1.288045e-4f;           // Delta^2 * (1/16) * log2(e)

#define AS1C(p) ((const __attribute__((address_space(1))) void*)(p))
#define AS3(p)  ((__attribute__((address_space(3))) void*)(p))

__device__ __forceinline__ v8bf ldfrag(const u16* p) {
    return __builtin_bit_cast(v8bf, *(const uint4*)p);
}
__device__ __forceinline__ u16 f2bf(float f) {
    return __builtin_bit_cast(u16, (__bf16)f);
}
__device__ __forceinline__ u8 f2i8(float f) {
    float t = fminf(fmaxf(f * QSC_, -127.f), 127.f);
    return (u8)(signed char)__float2int_rn(t);
}

// ---------------- W fp32 -> bf16, plus zero-init of Z/w/out ----------------
__global__ void k_convw(const float* __restrict__ Wf, u16* __restrict__ Wb,
                        float* __restrict__ Z, float* __restrict__ w,
                        float* __restrict__ out) {
    int i = blockIdx.x * 256 + threadIdx.x;           // grid 512 -> 131072
    Wb[i] = f2bf(Wf[i]);
    if (i < B_ * S_) { Z[i] = 0.f; w[i] = 0.f; }
    if (i < B_ * D_) out[i] = 0.f;
}

// ---------------- projection: QK = x @ W^T + b -> i8 Q,K -------------------
__global__ __launch_bounds__(256) void k_proj(const float* __restrict__ x,
                                              const u16* __restrict__ Wb,
                                              const float* __restrict__ bias,
                                              u8* __restrict__ Qi,
                                              u8* __restrict__ Ki) {
    const int tid = threadIdx.x, wave = tid >> 6, lane = tid & 63;
    const int l15 = lane & 15, quad = lane >> 4;
    const int tt = blockIdx.x * 2 + (wave >> 1);       // token tile 0..1023
    const int wsel = wave & 1;                         // 0 -> Q, 1 -> K
    const int tbase = tt * 16;

    v8bf a[8];
    const float* xrow = x + (size_t)(tbase + l15) * D_ + quad * 8;
#pragma unroll
    for (int j = 0; j < 8; ++j) {
        float4 f0 = *(const float4*)(xrow + j * 32);
        float4 f1 = *(const float4*)(xrow + j * 32 + 4);
        v8bf t;
        t[0] = (__bf16)f0.x; t[1] = (__bf16)f0.y; t[2] = (__bf16)f0.z; t[3] = (__bf16)f0.w;
        t[4] = (__bf16)f1.x; t[5] = (__bf16)f1.y; t[6] = (__bf16)f1.z; t[7] = (__bf16)f1.w;
        a[j] = t;
    }

    u8* dst = wsel ? Ki : Qi;
    const u16* wbase = Wb + (size_t)(wsel * 256 + l15) * D_ + quad * 8;
    const float* bb = bias + wsel * 256;

    v8bf wcur[8], wnxt[8];
#pragma unroll
    for (int j = 0; j < 8; ++j) wcur[j] = ldfrag(wbase + j * 32);

    auto tile = [&](const v8bf (&wb)[8], int nt) {
        v4f acc = {0.f, 0.f, 0.f, 0.f};
#pragma unroll
        for (int j = 0; j < 8; ++j)
            acc = __builtin_amdgcn_mfma_f32_16x16x32_bf16(a[j], wb[j], acc, 0, 0, 0);
        const int col = nt * 16 + l15;                 // 0..255 within Q or K
        const float bv = bb[col];
#pragma unroll
        for (int r = 0; r < 4; ++r) {
            const int tok = tbase + quad * 4 + r;
            dst[tok * D_ + col] = f2i8(acc[r] + bv);
        }
    };

    for (int nt = 0; nt < 16; nt += 2) {
        const u16* wp1 = wbase + (size_t)(nt + 1) * 16 * D_;
#pragma unroll
        for (int j = 0; j < 8; ++j) wnxt[j] = ldfrag(wp1 + j * 32);
        tile(wcur, nt);
        if (nt + 2 < 16) {
            const u16* wp2 = wbase + (size_t)(nt + 2) * 16 * D_;
#pragma unroll
            for (int j = 0; j < 8; ++j) wcur[j] = ldfrag(wp2 + j * 32);
        }
        tile(wnxt, nt + 1);
    }
}

// Stage a 64-row x 256B i8 tile into LDS (16 KB), XOR-swizzled:
// LDS slot (R,P) holds global chunk c = P ^ (R&15). Read side: fragment
// (kc,quad) of row l15 lives at P = (kc*4+quad) ^ l15 -> uniform bank spread.
// [verified round 5: SQ_LDS_BANK_CONFLICT == 0]
__device__ __forceinline__ void stage64(const u8* src, u8* dst,
                                        int wave, int lane) {
#pragma unroll
    for (int v = 0; v < 4; ++v) {
        const int sbase = v * 256 + wave * 64;         // wave-uniform slot base
        const int slot = sbase + lane;
        const int R = slot >> 4, P = slot & 15;
        const int c = P ^ (R & 15);
        __builtin_amdgcn_global_load_lds(AS1C(src + R * 256 + c * 16),
                                         AS3(dst + sbase * 16), 16, 0, 0);
    }
}

// ---------------- pass A: Z_q = sum_k exp2(dot_i32 * DQ) -------------------
// Stationary: 64 q rows/wave (4 sets, VGPR=128 — spill-safe, 4 waves/SIMD).
// Streamed: 4 x 64-key tiles via LDS ring. Grid 1024 = 4 blocks/CU.
__global__ __launch_bounds__(256, 2) void k_passA(const u8* __restrict__ Qi,
                                                  const u8* __restrict__ Ki,
                                                  float* __restrict__ Z) {
    __shared__ u8 sK[2][16384];
    const int tid = threadIdx.x, wave = tid >> 6, lane = tid & 63;
    const int l15 = lane & 15, quad = lane >> 4;
    const int blk = blockIdx.x;                 // 1024 = b(4) x qg(16) x ks(16)
    const int ks = blk & 15;                    // low bits -> XCD-spread streams
    const int qg = (blk >> 4) & 15;
    const int b = blk >> 8;
    const int qbase = qg * 256 + wave * 64;
    const int kstart = ks * 256;

    v4i a[4][4];
    {
        const u8* qp = Qi + (size_t)(b * S_ + qbase + l15) * D_ + quad * 16;
#pragma unroll
        for (int s = 0; s < 4; ++s)
#pragma unroll
            for (int c = 0; c < 4; ++c)
                a[s][c] = *(const v4i*)(qp + s * 16 * D_ + c * 64);
    }
    float z[4][4];
#pragma unroll
    for (int s = 0; s < 4; ++s)
#pragma unroll
        for (int r = 0; r < 4; ++r) z[s][r] = 0.f;

    const u8* kb = Ki + (size_t)(b * S_ + kstart) * D_;
    stage64(kb, sK[0], wave, lane);

    for (int t = 0; t < 4; ++t) {
        __syncthreads();
        if (t + 1 < 4) stage64(kb + (size_t)(t + 1) * 64 * D_, sK[(t + 1) & 1], wave, lane);
        const u8* base = sK[t & 1];
#pragma unroll
        for (int u = 0; u < 4; ++u) {          // 4 subtiles of 16 keys
            v4i bf[4];
#pragma unroll
            for (int kc = 0; kc < 4; ++kc) {
                const int P = (kc * 4 + quad) ^ l15;
                bf[kc] = *(const v4i*)(base + (u * 16 + l15) * 256 + P * 16);
            }
            v4i c0 = {0,0,0,0}, c1 = {0,0,0,0}, c2 = {0,0,0,0}, c3 = {0,0,0,0};
#pragma unroll
            for (int kc = 0; kc < 4; ++kc) {
                c0 = __builtin_amdgcn_mfma_i32_16x16x64_i8(a[0][kc], bf[kc], c0, 0, 0, 0);
                c1 = __builtin_amdgcn_mfma_i32_16x16x64_i8(a[1][kc], bf[kc], c1, 0, 0, 0);
                c2 = __builtin_amdgcn_mfma_i32_16x16x64_i8(a[2][kc], bf[kc], c2, 0, 0, 0);
                c3 = __builtin_amdgcn_mfma_i32_16x16x64_i8(a[3][kc], bf[kc], c3, 0, 0, 0);
            }
#pragma unroll
            for (int r = 0; r < 4; ++r) {
                z[0][r] += __builtin_amdgcn_exp2f((float)c0[r] * DQ_);
                z[1][r] += __builtin_amdgcn_exp2f((float)c1[r] * DQ_);
                z[2][r] += __builtin_amdgcn_exp2f((float)c2[r] * DQ_);
                z[3][r] += __builtin_amdgcn_exp2f((float)c3[r] * DQ_);
            }
        }
    }

#pragma unroll
    for (int s = 0; s < 4; ++s)
#pragma unroll
        for (int r = 0; r < 4; ++r) {
            float v = z[s][r];
#pragma unroll
            for (int off = 1; off < 16; off <<= 1) v += __shfl_xor(v, off);
            if (l15 == 0) atomicAdd(&Z[b * S_ + qbase + s * 16 + quad * 4 + r], v);
        }
}

// ---------------- pass B: w_k = sum_q exp2(dot_i32 * DQ) / Z_q -------------
// Stationary: 64 k rows/wave (4 sets). Streamed: 4 x 64-query tiles + Z.
__global__ __launch_bounds__(256, 2) void k_passB(const u8* __restrict__ Qi,
                                                  const u8* __restrict__ Ki,
                                                  const float* __restrict__ Zs,
                                                  float* __restrict__ w) {
    __shared__ u8 sQ[2][16384];
    const int tid = threadIdx.x, wave = tid >> 6, lane = tid & 63;
    const int l15 = lane & 15, quad = lane >> 4;
    const int blk = blockIdx.x;                 // 1024 = b(4) x kg(16) x qs(16)
    const int qs = blk & 15;
    const int kg = (blk >> 4) & 15;
    const int b = blk >> 8;
    const int kbase = kg * 256 + wave * 64;
    const int qstart = qs * 256;

    v4i bk[4][4];
    {
        const u8* kp = Ki + (size_t)(b * S_ + kbase + l15) * D_ + quad * 16;
#pragma unroll
        for (int s = 0; s < 4; ++s)
#pragma unroll
            for (int c = 0; c < 4; ++c)
                bk[s][c] = *(const v4i*)(kp + s * 16 * D_ + c * 64);
    }
    float wsum[4] = {0.f, 0.f, 0.f, 0.f};

    const u8* qb = Qi + (size_t)(b * S_ + qstart) * D_;
    stage64(qb, sQ[0], wave, lane);
    const float* zrow = Zs + b * S_ + qstart + quad * 4;

    for (int t = 0; t < 4; ++t) {
        __syncthreads();
        if (t + 1 < 4) stage64(qb + (size_t)(t + 1) * 64 * D_, sQ[(t + 1) & 1], wave, lane);
        const u8* base = sQ[t & 1];
#pragma unroll
        for (int u = 0; u < 4; ++u) {          // 4 subtiles of 16 queries
            const float4 Zv = *(const float4*)(zrow + t * 64 + u * 16);
            v4i af[4];
#pragma unroll
            for (int kc = 0; kc < 4; ++kc) {
                const int P = (kc * 4 + quad) ^ l15;
                af[kc] = *(const v4i*)(base + (u * 16 + l15) * 256 + P * 16);
            }
            v4i c0 = {0,0,0,0}, c1 = {0,0,0,0}, c2 = {0,0,0,0}, c3 = {0,0,0,0};
#pragma unroll
            for (int kc = 0; kc < 4; ++kc) {
                c0 = __builtin_amdgcn_mfma_i32_16x16x64_i8(af[kc], bk[0][kc], c0, 0, 0, 0);
                c1 = __builtin_amdgcn_mfma_i32_16x16x64_i8(af[kc], bk[1][kc], c1, 0, 0, 0);
                c2 = __builtin_amdgcn_mfma_i32_16x16x64_i8(af[kc], bk[2][kc], c2, 0, 0, 0);
                c3 = __builtin_amdgcn_mfma_i32_16x16x64_i8(af[kc], bk[3][kc], c3, 0, 0, 0);
            }
            const float rz0 = __builtin_amdgcn_rcpf(Zv.x);
            const float rz1 = __builtin_amdgcn_rcpf(Zv.y);
            const float rz2 = __builtin_amdgcn_rcpf(Zv.z);
            const float rz3 = __builtin_amdgcn_rcpf(Zv.w);
            wsum[0] += __builtin_amdgcn_exp2f((float)c0[0] * DQ_) * rz0 + __builtin_amdgcn_exp2f((float)c0[1] * DQ_) * rz1
                     + __builtin_amdgcn_exp2f((float)c0[2] * DQ_) * rz2 + __builtin_amdgcn_exp2f((float)c0[3] * DQ_) * rz3;
            wsum[1] += __builtin_amdgcn_exp2f((float)c1[0] * DQ_) * rz0 + __builtin_amdgcn_exp2f((float)c1[1] * DQ_) * rz1
                     + __builtin_amdgcn_exp2f((float)c1[2] * DQ_) * rz2 + __builtin_amdgcn_exp2f((float)c1[3] * DQ_) * rz3;
            wsum[2] += __builtin_amdgcn_exp2f((float)c2[0] * DQ_) * rz0 + __builtin_amdgcn_exp2f((float)c2[1] * DQ_) * rz1
                     + __builtin_amdgcn_exp2f((float)c2[2] * DQ_) * rz2 + __builtin_amdgcn_exp2f((float)c2[3] * DQ_) * rz3;
            wsum[3] += __builtin_amdgcn_exp2f((float)c3[0] * DQ_) * rz0 + __builtin_amdgcn_exp2f((float)c3[1] * DQ_) * rz1
                     + __builtin_amdgcn_exp2f((float)c3[2] * DQ_) * rz2 + __builtin_amdgcn_exp2f((float)c3[3] * DQ_) * rz3;
        }
    }

#pragma unroll
    for (int s = 0; s < 4; ++s) {
        wsum[s] += __shfl_xor(wsum[s], 16);
        wsum[s] += __shfl_xor(wsum[s], 32);
        if (quad == 0) atomicAdd(&w[b * S_ + kbase + s * 16 + l15], wsum[s]);
    }
}

// ---------------- final: out[b,d] = sum_k w[b,k] * x[b,k,d] ----------------
__global__ __launch_bounds__(256) void k_final(const float* __restrict__ x,
                                               const float* __restrict__ w,
                                               float* __restrict__ out) {
    const int b = blockIdx.x >> 5, kc = blockIdx.x & 31;  // grid 128
    const int d = threadIdx.x;
    const int k0 = kc * 128;
    float acc = 0.f;
    const float* xp = x + (size_t)(b * S_ + k0) * D_ + d;
    const float* wp = w + b * S_ + k0;
#pragma unroll 8
    for (int kk = 0; kk < 128; ++kk) acc += wp[kk] * xp[(size_t)kk * D_];
    atomicAdd(&out[b * D_ + d], acc);
}

extern "C" void kernel_launch(void* const* d_in, const int* in_sizes, int n_in,
                              void* d_out, int out_size, void* d_ws, size_t ws_size,
                              hipStream_t stream) {
    const float* x    = (const float*)d_in[0];   // [4,4096,256]
    const float* W    = (const float*)d_in[1];   // [512,256]
    const float* bias = (const float*)d_in[2];   // [512]
    float* out = (float*)d_out;                  // [4,256]

    char* ws = (char*)d_ws;
    u8*    Qi = (u8*)ws;                                  // 4 MiB
    u8*    Ki = Qi + (size_t)B_ * S_ * D_;                // 4 MiB
    float* Z  = (float*)(ws + 8388608);                   // 64 KiB
    float* w  = Z + B_ * S_;                              // 64 KiB
    u16*   Wb = (u16*)(w + B_ * S_);                      // 256 KiB

    k_convw<<<E_ * D_ / 256, 256, 0, stream>>>(W, Wb, Z, w, out);
    k_proj <<<512, 256, 0, stream>>>(x, Wb, bias, Qi, Ki);
    k_passA<<<1024, 256, 0, stream>>>(Qi, Ki, Z);
    k_passB<<<1024, 256, 0, stream>>>(Qi, Ki, Z, w);
    k_final<<<128, 256, 0, stream>>>(x, w, out);
}